// Round 9
// baseline (310.826 us; speedup 1.0000x reference)
//
#include <hip/hip_runtime.h>
#include <math.h>

#define N_NODES 50000
#define N_EDGES 800000
#define F_IN    86
#define H_DIM   128
#define ED_DIM  16
#define C_CLS   18
#define G_GRAPHS 64
#define NEG_SLOPE 0.2f
#define SCAN_BLOCKS ((N_NODES + 255) / 256)   // 196
#define EB_BLOCKS ((N_EDGES + 255) / 256)     // 3125
#define GB_BLOCKS ((N_NODES + 63) / 64)       // 782
#define HB_BLOCKS 782                          // hist blocks in merged kernel
#define HB_THREADS (HB_BLOCKS * 256)           // 200192; 4 edges/thread

typedef _Float16 h2v   __attribute__((ext_vector_type(2)));
typedef _Float16 half8 __attribute__((ext_vector_type(8)));
typedef float    f4v   __attribute__((ext_vector_type(4)));
typedef unsigned long long ull;

__device__ __forceinline__ void atomicMaxFloat(float* addr, float val) {
    if (val >= 0.0f) atomicMax((int*)addr, __float_as_int(val));
    else             atomicMin((unsigned int*)addr, __float_as_uint(val));
}

// zero cnt0/cnt1; ve1/ve2 + zero pooled; W1t/W2t fp16 transposes.
__global__ void prep(int* __restrict__ cnt0, int* __restrict__ cnt1,
                     float* __restrict__ pooled,
                     const float* __restrict__ We1, const float* __restrict__ ae1,
                     const float* __restrict__ We2, const float* __restrict__ ae2,
                     float* __restrict__ ve1, float* __restrict__ ve2,
                     const float* __restrict__ W1, const float* __restrict__ W2,
                     _Float16* __restrict__ w1t, _Float16* __restrict__ w2t) {
    int b = blockIdx.x, t = threadIdx.x;
    if (b < SCAN_BLOCKS) {
        int i = b * 256 + t;
        if (i < N_NODES) { cnt0[i] = 0; cnt1[i] = 0; }
    } else if (b == SCAN_BLOCKS) {
        if (t < ED_DIM) {
            float s = 0.f;
            for (int h = 0; h < H_DIM; ++h) s += We1[t * H_DIM + h] * ae1[h];
            ve1[t] = s;
        } else if (t < 2 * ED_DIM) {
            int j = t - ED_DIM;
            float s = 0.f;
            for (int h = 0; h < H_DIM; ++h) s += We2[j * H_DIM + h] * ae2[h];
            ve2[j] = s;
        }
        for (int i = t; i < G_GRAPHS * H_DIM; i += 256) pooled[i] = 0.f;
    } else if (b == SCAN_BLOCKS + 1) {
        for (int i = t; i < H_DIM * 96; i += 256) {
            int n = i / 96, k = i - n * 96;
            w1t[i] = (k < F_IN) ? (_Float16)W1[k * H_DIM + n] : (_Float16)0.f;
        }
    } else {
        for (int i = t; i < H_DIM * H_DIM; i += 256) {
            int n = i >> 7, k = i & 127;
            w2t[i] = (_Float16)W2[k * H_DIM + n];
        }
    }
}

// per-block inclusive scan over (cnt0+cnt1) -> excl + block sums
__global__ void scan1(const int* __restrict__ cnt0, const int* __restrict__ cnt1,
                      int* __restrict__ excl, int* __restrict__ bsum) {
    __shared__ int s[256];
    int tid = threadIdx.x;
    int i = blockIdx.x * 256 + tid;
    int v = (i < N_NODES) ? cnt0[i] + cnt1[i] : 0;
    s[tid] = v;
    __syncthreads();
    for (int o = 1; o < 256; o <<= 1) {
        int t = (tid >= o) ? s[tid - o] : 0;
        __syncthreads();
        s[tid] += t;
        __syncthreads();
    }
    if (i < N_NODES) excl[i] = s[tid] - v;
    if (tid == 255) bsum[blockIdx.x] = s[255];
}

// scan23 folded into scatter + ea-dots moved here (coalesced 51 MB stream at
// full BW instead of inside the atomic-bound hist). Every block scans the 196
// block sums in LDS; blocks 0..195 also write row_ptr. Edge bank (e&1) edges
// are offset by cnt0[d] within the row (arbitrary-but-valid permutation).
__global__ void scan_scatter(const int* __restrict__ excl, const int* __restrict__ bsum,
                             int* __restrict__ row_ptr,
                             const int* __restrict__ src, const int* __restrict__ dst,
                             const unsigned short* __restrict__ rank,
                             const int* __restrict__ cnt0,
                             const float* __restrict__ ea,
                             const float* __restrict__ ve1, const float* __restrict__ ve2,
                             int2* __restrict__ perm) {
    __shared__ int s[256];
    int tid = threadIdx.x;
    int v = (tid < SCAN_BLOCKS) ? bsum[tid] : 0;
    s[tid] = v;
    __syncthreads();
    for (int o = 1; o < 256; o <<= 1) {
        int t = (tid >= o) ? s[tid - o] : 0;
        __syncthreads();
        s[tid] += t;
        __syncthreads();
    }
    int eb = s[tid] - v;          // exclusive offset of node-block tid
    __syncthreads();
    s[tid] = eb;
    __syncthreads();
    int e = blockIdx.x * 256 + tid;
    if (blockIdx.x < SCAN_BLOCKS) {
        if (e < N_NODES) row_ptr[e] = excl[e] + s[e >> 8];
        if (e == 0) row_ptr[N_NODES] = N_EDGES;
    }
    if (e < N_EDGES) {
        int d = dst[e];
        int base = excl[d] + s[d >> 8];
        int off = (e & 1) ? cnt0[d] : 0;
        int pos = base + off + rank[e];
        const float4* p = (const float4*)(ea + (size_t)e * ED_DIM);
        float4 v0 = p[0], v1 = p[1], v2 = p[2], v3 = p[3];
        float s1 = v0.x*ve1[0] + v0.y*ve1[1] + v0.z*ve1[2] + v0.w*ve1[3]
                 + v1.x*ve1[4] + v1.y*ve1[5] + v1.z*ve1[6] + v1.w*ve1[7]
                 + v2.x*ve1[8] + v2.y*ve1[9] + v2.z*ve1[10] + v2.w*ve1[11]
                 + v3.x*ve1[12] + v3.y*ve1[13] + v3.z*ve1[14] + v3.w*ve1[15];
        float s2 = v0.x*ve2[0] + v0.y*ve2[1] + v0.z*ve2[2] + v0.w*ve2[3]
                 + v1.x*ve2[4] + v1.y*ve2[5] + v1.z*ve2[6] + v1.w*ve2[7]
                 + v2.x*ve2[8] + v2.y*ve2[9] + v2.z*ve2[10] + v2.w*ve2[11]
                 + v3.x*ve2[12] + v3.y*ve2[13] + v3.z*ve2[14] + v3.w*ve2[15];
        h2v dv;
        dv.x = (_Float16)s1;
        dv.y = (_Float16)s2;
        perm[pos] = make_int2(src[e], (int)__builtin_bit_cast(unsigned int, dv));
    }
}

// Merged conv1 GEMM + lean split-bank histogram. Blocks [0, GB_BLOCKS): gemm1
// (A staged in LDS, B from L1-resident W1t). Blocks [GB_BLOCKS, +HB_BLOCKS):
// lean hist, 4 edges/thread, bank by edge parity -> same-address atomic
// chains halve (16 -> 8 avg). No device fences (R5 lesson).
#define KP1 104
__global__ __launch_bounds__(256)
void gemm1_hist(const float* __restrict__ in, const _Float16* __restrict__ w1t,
                const float* __restrict__ a_s, const float* __restrict__ a_d,
                _Float16* __restrict__ hout, float* __restrict__ hs, float* __restrict__ hd,
                const int* __restrict__ dst, int* __restrict__ cnt0, int* __restrict__ cnt1,
                unsigned short* __restrict__ rank) {
    __shared__ __attribute__((aligned(16))) _Float16 Asm[64 * KP1];
    __shared__ float sdots[64][2][2];
    int tid = threadIdx.x;

    if (blockIdx.x >= GB_BLOCKS) {
        // ---- lean histogram: dst load + returning atomic + rank store ----
        int tbase = (blockIdx.x - GB_BLOCKS) * 256 + tid;
        int* bank = (tbase & 1) ? cnt1 : cnt0;
#pragma unroll
        for (int u = 0; u < 4; ++u) {
            int e = tbase + u * HB_THREADS;
            if (e < N_EDGES) {
                int r = atomicAdd(&bank[dst[e]], 1);
                rank[e] = (unsigned short)r;
            }
        }
        return;
    }

    // ---- gemm1 body (B from global W1t) ----
    int n0 = blockIdx.x * 64;
    const float2* in2 = (const float2*)(in + (size_t)n0 * F_IN);
    for (int idx = tid; idx < 64 * (F_IN / 2); idx += 256) {
        int r = idx / (F_IN / 2), k2 = idx - r * (F_IN / 2);
        float2 v = (n0 + r < N_NODES) ? in2[idx] : make_float2(0.f, 0.f);
        Asm[r * KP1 + 2 * k2]     = (_Float16)v.x;
        Asm[r * KP1 + 2 * k2 + 1] = (_Float16)v.y;
    }
    for (int idx = tid; idx < 64 * (96 - F_IN); idx += 256) {
        int r = idx / (96 - F_IN), k = F_IN + idx - r * (96 - F_IN);
        Asm[r * KP1 + k] = (_Float16)0.f;
    }
    __syncthreads();

    int wave = tid >> 6, lane = tid & 63;
    int wm = (wave & 1) * 32, wn = (wave >> 1) * 64;
    int m16 = lane & 15, quad = lane >> 4;

    f4v acc[2][4];
#pragma unroll
    for (int t = 0; t < 2; ++t)
#pragma unroll
        for (int c = 0; c < 4; ++c) acc[t][c] = (f4v){0.f, 0.f, 0.f, 0.f};

#pragma unroll
    for (int kk = 0; kk < 96 / 32; ++kk) {
        int koff = kk * 32 + quad * 8;
        half8 a0 = *(const half8*)&Asm[(wm + m16) * KP1 + koff];
        half8 a1 = *(const half8*)&Asm[(wm + 16 + m16) * KP1 + koff];
#pragma unroll
        for (int c = 0; c < 4; ++c) {
            half8 b = *(const half8*)&w1t[(wn + c * 16 + m16) * 96 + koff];
            acc[0][c] = __builtin_amdgcn_mfma_f32_16x16x32_f16(a0, b, acc[0][c], 0, 0, 0);
            acc[1][c] = __builtin_amdgcn_mfma_f32_16x16x32_f16(a1, b, acc[1][c], 0, 0, 0);
        }
    }

    float asv[4], adv[4];
#pragma unroll
    for (int c = 0; c < 4; ++c) {
        asv[c] = a_s[wn + c * 16 + m16];
        adv[c] = a_d[wn + c * 16 + m16];
    }
#pragma unroll
    for (int t = 0; t < 2; ++t)
#pragma unroll
        for (int r = 0; r < 4; ++r) {
            float ps = 0.f, pd = 0.f;
#pragma unroll
            for (int c = 0; c < 4; ++c) {
                float v = acc[t][c][r];
                ps += v * asv[c];
                pd += v * adv[c];
            }
#pragma unroll
            for (int o = 1; o < 16; o <<= 1) {
                ps += __shfl_xor(ps, o);
                pd += __shfl_xor(pd, o);
            }
            if (m16 == 0) {
                int row = wm + t * 16 + quad * 4 + r;
                sdots[row][wn >> 6][0] = ps;
                sdots[row][wn >> 6][1] = pd;
            }
        }
#pragma unroll
    for (int t = 0; t < 2; ++t)
#pragma unroll
        for (int c = 0; c < 4; ++c)
#pragma unroll
            for (int r = 0; r < 4; ++r) {
                int row = n0 + wm + t * 16 + quad * 4 + r;
                if (row < N_NODES)
                    hout[(size_t)row * H_DIM + wn + c * 16 + m16] = (_Float16)acc[t][c][r];
            }
    __syncthreads();
    if (tid < 64) {
        int row = n0 + tid;
        if (row < N_NODES) {
            hs[row] = sdots[tid][0][0] + sdots[tid][1][0];
            hd[row] = sdots[tid][0][1] + sdots[tid][1][1];
        }
    }
}

// conv2 GEMM + fused node dots. fp16 input, K=128; B from global W2t.
#define KP2 136
__global__ __launch_bounds__(256)
void gemm2(const _Float16* __restrict__ in, const _Float16* __restrict__ w2t,
           const float* __restrict__ a_s, const float* __restrict__ a_d,
           _Float16* __restrict__ hout, float* __restrict__ hs, float* __restrict__ hd) {
    __shared__ __attribute__((aligned(16))) _Float16 Asm[64 * KP2];
    __shared__ float sdots[64][2][2];
    int tid = threadIdx.x;
    int n0 = blockIdx.x * 64;

    const half8* in8 = (const half8*)(in + (size_t)n0 * H_DIM);
    for (int idx = tid; idx < 64 * 16; idx += 256) {
        int r = idx >> 4, k8 = idx & 15;
        half8 v = (n0 + r < N_NODES) ? in8[idx]
                                     : (half8){0, 0, 0, 0, 0, 0, 0, 0};
        *(half8*)&Asm[r * KP2 + k8 * 8] = v;
    }
    __syncthreads();

    int wave = tid >> 6, lane = tid & 63;
    int wm = (wave & 1) * 32, wn = (wave >> 1) * 64;
    int m16 = lane & 15, quad = lane >> 4;

    f4v acc[2][4];
#pragma unroll
    for (int t = 0; t < 2; ++t)
#pragma unroll
        for (int c = 0; c < 4; ++c) acc[t][c] = (f4v){0.f, 0.f, 0.f, 0.f};

#pragma unroll
    for (int kk = 0; kk < 128 / 32; ++kk) {
        int koff = kk * 32 + quad * 8;
        half8 a0 = *(const half8*)&Asm[(wm + m16) * KP2 + koff];
        half8 a1 = *(const half8*)&Asm[(wm + 16 + m16) * KP2 + koff];
#pragma unroll
        for (int c = 0; c < 4; ++c) {
            half8 b = *(const half8*)&w2t[(wn + c * 16 + m16) * H_DIM + koff];
            acc[0][c] = __builtin_amdgcn_mfma_f32_16x16x32_f16(a0, b, acc[0][c], 0, 0, 0);
            acc[1][c] = __builtin_amdgcn_mfma_f32_16x16x32_f16(a1, b, acc[1][c], 0, 0, 0);
        }
    }

    float asv[4], adv[4];
#pragma unroll
    for (int c = 0; c < 4; ++c) {
        asv[c] = a_s[wn + c * 16 + m16];
        adv[c] = a_d[wn + c * 16 + m16];
    }
#pragma unroll
    for (int t = 0; t < 2; ++t)
#pragma unroll
        for (int r = 0; r < 4; ++r) {
            float ps = 0.f, pd = 0.f;
#pragma unroll
            for (int c = 0; c < 4; ++c) {
                float v = acc[t][c][r];
                ps += v * asv[c];
                pd += v * adv[c];
            }
#pragma unroll
            for (int o = 1; o < 16; o <<= 1) {
                ps += __shfl_xor(ps, o);
                pd += __shfl_xor(pd, o);
            }
            if (m16 == 0) {
                int row = wm + t * 16 + quad * 4 + r;
                sdots[row][wn >> 6][0] = ps;
                sdots[row][wn >> 6][1] = pd;
            }
        }
#pragma unroll
    for (int t = 0; t < 2; ++t)
#pragma unroll
        for (int c = 0; c < 4; ++c)
#pragma unroll
            for (int r = 0; r < 4; ++r) {
                int row = n0 + wm + t * 16 + quad * 4 + r;
                if (row < N_NODES)
                    hout[(size_t)row * H_DIM + wn + c * 16 + m16] = (_Float16)acc[t][c][r];
            }
    __syncthreads();
    if (tid < 64) {
        int row = n0 + tid;
        if (row < N_NODES) {
            hs[row] = sdots[tid][0][0] + sdots[tid][1][0];
            hd[row] = sdots[tid][0][1] + sdots[tid][1][1];
        }
    }
}

// One wave per dst node, single-pass softmax; LDS stage for {so,w} broadcast.
// POOL=true fuses only the global max-pool (no device fences — R5 lesson).
template<int DOT, bool POOL>
__global__ void gat_node(const int* __restrict__ row_ptr, const int2* __restrict__ perm,
                         const float* __restrict__ hs, const float* __restrict__ hd,
                         const _Float16* __restrict__ h, const float* __restrict__ bias,
                         _Float16* __restrict__ out,
                         const int* __restrict__ batch, float* __restrict__ pooled) {
    __shared__ float smax[H_DIM];
    __shared__ int sg[4];
    __shared__ __attribute__((aligned(16))) ull stage[4][64];
    int tid = threadIdx.x;
    if (POOL) {
        if (tid < H_DIM) smax[tid] = 0.f;
        __syncthreads();
    }
    int n = blockIdx.x * 4 + (tid >> 6);
    int lane = tid & 63;
    int q = lane >> 4, m = lane & 15;
    int r0 = row_ptr[n], r1 = row_ptr[n + 1];
    float hdn = hd[n];
    const char* hb = (const char*)h;
    unsigned mo = (unsigned)(m * 16);   // lane's byte offset within a row
    ull* st = stage[tid >> 6];

    float acc[8];
#pragma unroll
    for (int k = 0; k < 8; ++k) acc[k] = 0.f;
    float denl = 0.f;

    for (int c = r0; c < r1; c += 64) {
        int i = c + lane;
        float w = 0.f;
        int so = 0;                      // byte offset of src row (fits 32-bit)
        if (i < r1) {
            int2 p = perm[i];
            so = p.x * (H_DIM * 2);
            h2v dv = __builtin_bit_cast(h2v, p.y);
            float dotv = (DOT == 1) ? (float)dv.x : (float)dv.y;
            float t = hs[p.x] + hdn + dotv;
            t = (t > 0.f) ? t : NEG_SLOPE * t;
            w = __expf(t);
        }
        denl += w;
        st[lane] = (ull)(unsigned)so | ((ull)__float_as_uint(w) << 32);
        int lim = r1 - c; if (lim > 64) lim = 64;
        int njj = (lim + 7) >> 3;
        int jj = 0;
        for (; jj + 2 <= njj; jj += 2) {
            int b8 = jj << 3;
            ull p1 = st[b8 + q];
            ull p2 = st[b8 + q + 4];
            ull p3 = st[b8 + q + 8];
            ull p4 = st[b8 + q + 12];
            float w1 = __uint_as_float((unsigned)(p1 >> 32));
            float w2 = __uint_as_float((unsigned)(p2 >> 32));
            float w3 = __uint_as_float((unsigned)(p3 >> 32));
            float w4 = __uint_as_float((unsigned)(p4 >> 32));
            half8 v1 = *(const half8*)(hb + ((unsigned)p1 + mo));
            half8 v2 = *(const half8*)(hb + ((unsigned)p2 + mo));
            half8 v3 = *(const half8*)(hb + ((unsigned)p3 + mo));
            half8 v4 = *(const half8*)(hb + ((unsigned)p4 + mo));
#pragma unroll
            for (int k = 0; k < 8; ++k) acc[k] += w1 * (float)v1[k];
#pragma unroll
            for (int k = 0; k < 8; ++k) acc[k] += w2 * (float)v2[k];
#pragma unroll
            for (int k = 0; k < 8; ++k) acc[k] += w3 * (float)v3[k];
#pragma unroll
            for (int k = 0; k < 8; ++k) acc[k] += w4 * (float)v4[k];
        }
        if (jj < njj) {
            int b8 = jj << 3;
            ull p1 = st[b8 + q];
            ull p2 = st[b8 + q + 4];
            float w1 = __uint_as_float((unsigned)(p1 >> 32));
            float w2 = __uint_as_float((unsigned)(p2 >> 32));
            half8 v1 = *(const half8*)(hb + ((unsigned)p1 + mo));
            half8 v2 = *(const half8*)(hb + ((unsigned)p2 + mo));
#pragma unroll
            for (int k = 0; k < 8; ++k) acc[k] += w1 * (float)v1[k];
#pragma unroll
            for (int k = 0; k < 8; ++k) acc[k] += w2 * (float)v2[k];
        }
    }
#pragma unroll
    for (int k = 0; k < 8; ++k) {
        acc[k] += __shfl_xor(acc[k], 16);
        acc[k] += __shfl_xor(acc[k], 32);
    }
    float den = denl;
#pragma unroll
    for (int o = 32; o > 0; o >>= 1) den += __shfl_xor(den, o);
    float inv = 1.f / fmaxf(den, 1e-16f);

    float rv[8];
    if (q == 0) {
        float4 b0 = ((const float4*)bias)[2 * m];
        float4 b1 = ((const float4*)bias)[2 * m + 1];
        rv[0] = fmaxf(acc[0] * inv + b0.x, 0.f);
        rv[1] = fmaxf(acc[1] * inv + b0.y, 0.f);
        rv[2] = fmaxf(acc[2] * inv + b0.z, 0.f);
        rv[3] = fmaxf(acc[3] * inv + b0.w, 0.f);
        rv[4] = fmaxf(acc[4] * inv + b1.x, 0.f);
        rv[5] = fmaxf(acc[5] * inv + b1.y, 0.f);
        rv[6] = fmaxf(acc[6] * inv + b1.z, 0.f);
        rv[7] = fmaxf(acc[7] * inv + b1.w, 0.f);
    }

    if (!POOL) {
        if (q == 0) {
            half8 ov;
#pragma unroll
            for (int k = 0; k < 8; ++k) ov[k] = (_Float16)rv[k];
            *(half8*)&out[(size_t)n * H_DIM + m * 8] = ov;
        }
    } else {
        int g = batch[n];
        if (lane == 0) sg[tid >> 6] = g;
        if (q == 0) {
#pragma unroll
            for (int k = 0; k < 8; ++k)
                atomicMax((int*)&smax[m * 8 + k], __float_as_int(rv[k]));  // rv >= 0
        }
        __syncthreads();
        if (sg[0] == sg[3]) {
            if (tid < H_DIM)
                atomicMaxFloat(&pooled[sg[0] * H_DIM + tid], smax[tid]);
        } else {
            if (q == 0) {
#pragma unroll
                for (int k = 0; k < 8; ++k)
                    atomicMaxFloat(&pooled[g * H_DIM + m * 8 + k], rv[k]);
            }
        }
    }
}

__global__ void final_logits(const float* __restrict__ pooled, const float* __restrict__ Wl,
                             const float* __restrict__ bl, float* __restrict__ outp) {
    int g = threadIdx.x;  // 64
    if (g >= G_GRAPHS) return;
    float lg[C_CLS];
#pragma unroll
    for (int c = 0; c < C_CLS; ++c) lg[c] = bl[c];
    for (int k = 0; k < H_DIM; ++k) {
        float v = pooled[g * H_DIM + k];
#pragma unroll
        for (int c = 0; c < C_CLS; ++c) lg[c] += v * Wl[k * C_CLS + c];
    }
    float mx = lg[0];
#pragma unroll
    for (int c = 1; c < C_CLS; ++c) mx = fmaxf(mx, lg[c]);
    float se = 0.f;
#pragma unroll
    for (int c = 0; c < C_CLS; ++c) se += expf(lg[c] - mx);
    float lse = logf(se);
#pragma unroll
    for (int c = 0; c < C_CLS; ++c) outp[g * C_CLS + c] = lg[c] - mx - lse;
}

extern "C" void kernel_launch(void* const* d_in, const int* in_sizes, int n_in,
                              void* d_out, int out_size, void* d_ws, size_t ws_size,
                              hipStream_t stream) {
    const float* x     = (const float*)d_in[0];
    const int*   eidx  = (const int*)d_in[1];
    const float* ea    = (const float*)d_in[2];
    const int*   batch = (const int*)d_in[3];
    const float* W1  = (const float*)d_in[4];
    const float* We1 = (const float*)d_in[5];
    const float* as1 = (const float*)d_in[6];
    const float* ad1 = (const float*)d_in[7];
    const float* ae1 = (const float*)d_in[8];
    const float* b1  = (const float*)d_in[9];
    const float* W2  = (const float*)d_in[10];
    const float* We2 = (const float*)d_in[11];
    const float* as2 = (const float*)d_in[12];
    const float* ad2 = (const float*)d_in[13];
    const float* ae2 = (const float*)d_in[14];
    const float* b2  = (const float*)d_in[15];
    const float* Wl  = (const float*)d_in[16];
    const float* bl  = (const float*)d_in[17];
    float* outp = (float*)d_out;

    const int* src = eidx;
    const int* dst = eidx + N_EDGES;

    char* wsb = (char*)d_ws;
    size_t off = 0;
    auto alloc = [&](size_t bytes) { char* p = wsb + off; off += (bytes + 255) & ~(size_t)255; return p; };
    _Float16* h    = (_Float16*)alloc((size_t)N_NODES * H_DIM * 2);
    _Float16* A2   = (_Float16*)alloc((size_t)N_NODES * H_DIM * 2);
    int2*  perm    = (int2*)alloc((size_t)N_EDGES * 8);
    unsigned short* rank = (unsigned short*)alloc((size_t)N_EDGES * 2);
    float* hs      = (float*)alloc(N_NODES * 4);
    float* hd      = (float*)alloc(N_NODES * 4);
    int*   row_ptr = (int*)alloc((N_NODES + 1) * 4);
    int*   cnt0    = (int*)alloc(N_NODES * 4);
    int*   cnt1    = (int*)alloc(N_NODES * 4);
    int*   excl    = (int*)alloc(N_NODES * 4);
    int*   bsum    = (int*)alloc(SCAN_BLOCKS * 4);
    float* pooled  = (float*)alloc(G_GRAPHS * H_DIM * 4);
    float* ve1     = (float*)alloc(16 * 4);
    float* ve2     = (float*)alloc(16 * 4);
    _Float16* w1t  = (_Float16*)alloc(H_DIM * 96 * 2);
    _Float16* w2t  = (_Float16*)alloc(H_DIM * H_DIM * 2);

    const int NB4 = (N_NODES + 3) / 4;

    // prep (incl. W1t/W2t transpose), then conv1-GEMM overlapped with lean hist
    prep<<<SCAN_BLOCKS + 3, 256, 0, stream>>>(cnt0, cnt1, pooled, We1, ae1, We2, ae2,
                                              ve1, ve2, W1, W2, w1t, w2t);
    gemm1_hist<<<GB_BLOCKS + HB_BLOCKS, 256, 0, stream>>>(x, w1t, as1, ad1, h, hs, hd,
                                                          dst, cnt0, cnt1, rank);
    scan1<<<SCAN_BLOCKS, 256, 0, stream>>>(cnt0, cnt1, excl, bsum);
    scan_scatter<<<EB_BLOCKS, 256, 0, stream>>>(excl, bsum, row_ptr, src, dst,
                                                rank, cnt0, ea, ve1, ve2, perm);

    // ---- conv1 aggregation ----
    gat_node<1, false><<<NB4, 256, 0, stream>>>(row_ptr, perm, hs, hd, h, b1, A2,
                                                batch, pooled);

    // ---- conv2 ----
    gemm2<<<GB_BLOCKS, 256, 0, stream>>>(A2, w2t, as2, ad2, h, hs, hd);
    gat_node<2, true><<<NB4, 256, 0, stream>>>(row_ptr, perm, hs, hd, h, b2, nullptr,
                                               batch, pooled);

    // ---- classifier ----
    final_logits<<<1, 64, 0, stream>>>(pooled, Wl, bl, outp);
}

// Round 10
// 301.439 us; speedup vs baseline: 1.0311x; 1.0311x over previous
//
#include <hip/hip_runtime.h>
#include <math.h>

#define N_NODES 50000
#define N_EDGES 800000
#define F_IN    86
#define H_DIM   128
#define ED_DIM  16
#define C_CLS   18
#define G_GRAPHS 64
#define NEG_SLOPE 0.2f
#define SCAN_BLOCKS ((N_NODES + 255) / 256)   // 196
#define EB_BLOCKS ((N_EDGES + 255) / 256)     // 3125
#define GB_BLOCKS ((N_NODES + 63) / 64)       // 782
#define HB_BLOCKS 782                          // hist blocks in merged kernel
#define HB_THREADS (HB_BLOCKS * 256)           // 200192 (mult of 4); 4 edges/thread

typedef _Float16 h2v   __attribute__((ext_vector_type(2)));
typedef _Float16 half8 __attribute__((ext_vector_type(8)));
typedef float    f4v   __attribute__((ext_vector_type(4)));
typedef unsigned long long ull;

__device__ __forceinline__ void atomicMaxFloat(float* addr, float val) {
    if (val >= 0.0f) atomicMax((int*)addr, __float_as_int(val));
    else             atomicMin((unsigned int*)addr, __float_as_uint(val));
}

// zero cnt4; ve1/ve2 + zero pooled; W1t/W2t fp16 transposes.
__global__ void prep(int4* __restrict__ cnt4, float* __restrict__ pooled,
                     const float* __restrict__ We1, const float* __restrict__ ae1,
                     const float* __restrict__ We2, const float* __restrict__ ae2,
                     float* __restrict__ ve1, float* __restrict__ ve2,
                     const float* __restrict__ W1, const float* __restrict__ W2,
                     _Float16* __restrict__ w1t, _Float16* __restrict__ w2t) {
    int b = blockIdx.x, t = threadIdx.x;
    if (b < SCAN_BLOCKS) {
        int i = b * 256 + t;
        if (i < N_NODES) cnt4[i] = make_int4(0, 0, 0, 0);
    } else if (b == SCAN_BLOCKS) {
        if (t < ED_DIM) {
            float s = 0.f;
            for (int h = 0; h < H_DIM; ++h) s += We1[t * H_DIM + h] * ae1[h];
            ve1[t] = s;
        } else if (t < 2 * ED_DIM) {
            int j = t - ED_DIM;
            float s = 0.f;
            for (int h = 0; h < H_DIM; ++h) s += We2[j * H_DIM + h] * ae2[h];
            ve2[j] = s;
        }
        for (int i = t; i < G_GRAPHS * H_DIM; i += 256) pooled[i] = 0.f;
    } else if (b == SCAN_BLOCKS + 1) {
        for (int i = t; i < H_DIM * 96; i += 256) {
            int n = i / 96, k = i - n * 96;
            w1t[i] = (k < F_IN) ? (_Float16)W1[k * H_DIM + n] : (_Float16)0.f;
        }
    } else {
        for (int i = t; i < H_DIM * H_DIM; i += 256) {
            int n = i >> 7, k = i & 127;
            w2t[i] = (_Float16)W2[k * H_DIM + n];
        }
    }
}

// per-block inclusive scan over sum(cnt4) -> excl + block sums
__global__ void scan1(const int4* __restrict__ cnt4, int* __restrict__ excl,
                      int* __restrict__ bsum) {
    __shared__ int s[256];
    int tid = threadIdx.x;
    int i = blockIdx.x * 256 + tid;
    int v = 0;
    if (i < N_NODES) {
        int4 c = cnt4[i];
        v = c.x + c.y + c.z + c.w;
    }
    s[tid] = v;
    __syncthreads();
    for (int o = 1; o < 256; o <<= 1) {
        int t = (tid >= o) ? s[tid - o] : 0;
        __syncthreads();
        s[tid] += t;
        __syncthreads();
    }
    if (i < N_NODES) excl[i] = s[tid] - v;
    if (tid == 255) bsum[blockIdx.x] = s[255];
}

// scan23 folded into scatter (lean: ea-dots stay in the overlapped hist —
// R9 lesson: don't move hidden streams onto the serial path). Bank prefix
// from cnt4: bank b edges sit after banks < b within the row.
__global__ void scan_scatter(const int* __restrict__ excl, const int* __restrict__ bsum,
                             int* __restrict__ row_ptr,
                             const int* __restrict__ src, const int* __restrict__ dst,
                             const unsigned short* __restrict__ rank,
                             const int4* __restrict__ cnt4,
                             const unsigned int* __restrict__ dotp,
                             int2* __restrict__ perm) {
    __shared__ int s[256];
    int tid = threadIdx.x;
    int v = (tid < SCAN_BLOCKS) ? bsum[tid] : 0;
    s[tid] = v;
    __syncthreads();
    for (int o = 1; o < 256; o <<= 1) {
        int t = (tid >= o) ? s[tid - o] : 0;
        __syncthreads();
        s[tid] += t;
        __syncthreads();
    }
    int eb = s[tid] - v;          // exclusive offset of node-block tid
    __syncthreads();
    s[tid] = eb;
    __syncthreads();
    int e = blockIdx.x * 256 + tid;
    if (blockIdx.x < SCAN_BLOCKS) {
        if (e < N_NODES) row_ptr[e] = excl[e] + s[e >> 8];
        if (e == 0) row_ptr[N_NODES] = N_EDGES;
    }
    if (e < N_EDGES) {
        int d = dst[e];
        int4 c = cnt4[d];
        int bank = e & 3;
        int off = (bank > 0 ? c.x : 0) + (bank > 1 ? c.y : 0) + (bank > 2 ? c.z : 0);
        int pos = excl[d] + s[d >> 8] + off + rank[e];
        perm[pos] = make_int2(src[e], (int)dotp[e]);
    }
}

// Merged conv1 GEMM + histogram/rank/edge-dots. Blocks [0, GB_BLOCKS): gemm1
// (A staged in LDS, B from L1-resident W1t). Blocks [GB_BLOCKS, +HB_BLOCKS):
// hist at 4 edges/thread with 4-way bank split (same-address chains 16 -> 4)
// + ea dots (51 MB stream hidden under the gemm blocks' MFMA). No device
// fences (R5 lesson).
#define KP1 104
__global__ __launch_bounds__(256)
void gemm1_hist(const float* __restrict__ in, const _Float16* __restrict__ w1t,
                const float* __restrict__ a_s, const float* __restrict__ a_d,
                _Float16* __restrict__ hout, float* __restrict__ hs, float* __restrict__ hd,
                const int* __restrict__ dst, int* __restrict__ cnt,
                unsigned short* __restrict__ rank, const float* __restrict__ ea,
                const float* __restrict__ ve1, const float* __restrict__ ve2,
                unsigned int* __restrict__ dotp) {
    __shared__ __attribute__((aligned(16))) _Float16 Asm[64 * KP1];
    __shared__ float sdots[64][2][2];
    int tid = threadIdx.x;

    if (blockIdx.x >= GB_BLOCKS) {
        // ---- histogram (4-way banked) + rank + edge-attr dots ----
        int tbase = (blockIdx.x - GB_BLOCKS) * 256 + tid;
        int bank = tbase & 3;          // e & 3 == tbase & 3 (HB_THREADS % 4 == 0)
#pragma unroll
        for (int u = 0; u < 4; ++u) {
            int e = tbase + u * HB_THREADS;
            if (e < N_EDGES) {
                int r = atomicAdd(&cnt[dst[e] * 4 + bank], 1);
                rank[e] = (unsigned short)r;
                const float4* p = (const float4*)(ea + (size_t)e * ED_DIM);
                float4 v0 = p[0], v1 = p[1], v2 = p[2], v3 = p[3];
                float s1 = v0.x*ve1[0] + v0.y*ve1[1] + v0.z*ve1[2] + v0.w*ve1[3]
                         + v1.x*ve1[4] + v1.y*ve1[5] + v1.z*ve1[6] + v1.w*ve1[7]
                         + v2.x*ve1[8] + v2.y*ve1[9] + v2.z*ve1[10] + v2.w*ve1[11]
                         + v3.x*ve1[12] + v3.y*ve1[13] + v3.z*ve1[14] + v3.w*ve1[15];
                float s2 = v0.x*ve2[0] + v0.y*ve2[1] + v0.z*ve2[2] + v0.w*ve2[3]
                         + v1.x*ve2[4] + v1.y*ve2[5] + v1.z*ve2[6] + v1.w*ve2[7]
                         + v2.x*ve2[8] + v2.y*ve2[9] + v2.z*ve2[10] + v2.w*ve2[11]
                         + v3.x*ve2[12] + v3.y*ve2[13] + v3.z*ve2[14] + v3.w*ve2[15];
                h2v dv;
                dv.x = (_Float16)s1;
                dv.y = (_Float16)s2;
                dotp[e] = __builtin_bit_cast(unsigned int, dv);
            }
        }
        return;
    }

    // ---- gemm1 body (B from global W1t) ----
    int n0 = blockIdx.x * 64;
    const float2* in2 = (const float2*)(in + (size_t)n0 * F_IN);
    for (int idx = tid; idx < 64 * (F_IN / 2); idx += 256) {
        int r = idx / (F_IN / 2), k2 = idx - r * (F_IN / 2);
        float2 v = (n0 + r < N_NODES) ? in2[idx] : make_float2(0.f, 0.f);
        Asm[r * KP1 + 2 * k2]     = (_Float16)v.x;
        Asm[r * KP1 + 2 * k2 + 1] = (_Float16)v.y;
    }
    for (int idx = tid; idx < 64 * (96 - F_IN); idx += 256) {
        int r = idx / (96 - F_IN), k = F_IN + idx - r * (96 - F_IN);
        Asm[r * KP1 + k] = (_Float16)0.f;
    }
    __syncthreads();

    int wave = tid >> 6, lane = tid & 63;
    int wm = (wave & 1) * 32, wn = (wave >> 1) * 64;
    int m16 = lane & 15, quad = lane >> 4;

    f4v acc[2][4];
#pragma unroll
    for (int t = 0; t < 2; ++t)
#pragma unroll
        for (int c = 0; c < 4; ++c) acc[t][c] = (f4v){0.f, 0.f, 0.f, 0.f};

#pragma unroll
    for (int kk = 0; kk < 96 / 32; ++kk) {
        int koff = kk * 32 + quad * 8;
        half8 a0 = *(const half8*)&Asm[(wm + m16) * KP1 + koff];
        half8 a1 = *(const half8*)&Asm[(wm + 16 + m16) * KP1 + koff];
#pragma unroll
        for (int c = 0; c < 4; ++c) {
            half8 b = *(const half8*)&w1t[(wn + c * 16 + m16) * 96 + koff];
            acc[0][c] = __builtin_amdgcn_mfma_f32_16x16x32_f16(a0, b, acc[0][c], 0, 0, 0);
            acc[1][c] = __builtin_amdgcn_mfma_f32_16x16x32_f16(a1, b, acc[1][c], 0, 0, 0);
        }
    }

    float asv[4], adv[4];
#pragma unroll
    for (int c = 0; c < 4; ++c) {
        asv[c] = a_s[wn + c * 16 + m16];
        adv[c] = a_d[wn + c * 16 + m16];
    }
#pragma unroll
    for (int t = 0; t < 2; ++t)
#pragma unroll
        for (int r = 0; r < 4; ++r) {
            float ps = 0.f, pd = 0.f;
#pragma unroll
            for (int c = 0; c < 4; ++c) {
                float v = acc[t][c][r];
                ps += v * asv[c];
                pd += v * adv[c];
            }
#pragma unroll
            for (int o = 1; o < 16; o <<= 1) {
                ps += __shfl_xor(ps, o);
                pd += __shfl_xor(pd, o);
            }
            if (m16 == 0) {
                int row = wm + t * 16 + quad * 4 + r;
                sdots[row][wn >> 6][0] = ps;
                sdots[row][wn >> 6][1] = pd;
            }
        }
#pragma unroll
    for (int t = 0; t < 2; ++t)
#pragma unroll
        for (int c = 0; c < 4; ++c)
#pragma unroll
            for (int r = 0; r < 4; ++r) {
                int row = n0 + wm + t * 16 + quad * 4 + r;
                if (row < N_NODES)
                    hout[(size_t)row * H_DIM + wn + c * 16 + m16] = (_Float16)acc[t][c][r];
            }
    __syncthreads();
    if (tid < 64) {
        int row = n0 + tid;
        if (row < N_NODES) {
            hs[row] = sdots[tid][0][0] + sdots[tid][1][0];
            hd[row] = sdots[tid][0][1] + sdots[tid][1][1];
        }
    }
}

// conv2 GEMM + fused node dots. fp16 input, K=128; B from global W2t.
#define KP2 136
__global__ __launch_bounds__(256)
void gemm2(const _Float16* __restrict__ in, const _Float16* __restrict__ w2t,
           const float* __restrict__ a_s, const float* __restrict__ a_d,
           _Float16* __restrict__ hout, float* __restrict__ hs, float* __restrict__ hd) {
    __shared__ __attribute__((aligned(16))) _Float16 Asm[64 * KP2];
    __shared__ float sdots[64][2][2];
    int tid = threadIdx.x;
    int n0 = blockIdx.x * 64;

    const half8* in8 = (const half8*)(in + (size_t)n0 * H_DIM);
    for (int idx = tid; idx < 64 * 16; idx += 256) {
        int r = idx >> 4, k8 = idx & 15;
        half8 v = (n0 + r < N_NODES) ? in8[idx]
                                     : (half8){0, 0, 0, 0, 0, 0, 0, 0};
        *(half8*)&Asm[r * KP2 + k8 * 8] = v;
    }
    __syncthreads();

    int wave = tid >> 6, lane = tid & 63;
    int wm = (wave & 1) * 32, wn = (wave >> 1) * 64;
    int m16 = lane & 15, quad = lane >> 4;

    f4v acc[2][4];
#pragma unroll
    for (int t = 0; t < 2; ++t)
#pragma unroll
        for (int c = 0; c < 4; ++c) acc[t][c] = (f4v){0.f, 0.f, 0.f, 0.f};

#pragma unroll
    for (int kk = 0; kk < 128 / 32; ++kk) {
        int koff = kk * 32 + quad * 8;
        half8 a0 = *(const half8*)&Asm[(wm + m16) * KP2 + koff];
        half8 a1 = *(const half8*)&Asm[(wm + 16 + m16) * KP2 + koff];
#pragma unroll
        for (int c = 0; c < 4; ++c) {
            half8 b = *(const half8*)&w2t[(wn + c * 16 + m16) * H_DIM + koff];
            acc[0][c] = __builtin_amdgcn_mfma_f32_16x16x32_f16(a0, b, acc[0][c], 0, 0, 0);
            acc[1][c] = __builtin_amdgcn_mfma_f32_16x16x32_f16(a1, b, acc[1][c], 0, 0, 0);
        }
    }

    float asv[4], adv[4];
#pragma unroll
    for (int c = 0; c < 4; ++c) {
        asv[c] = a_s[wn + c * 16 + m16];
        adv[c] = a_d[wn + c * 16 + m16];
    }
#pragma unroll
    for (int t = 0; t < 2; ++t)
#pragma unroll
        for (int r = 0; r < 4; ++r) {
            float ps = 0.f, pd = 0.f;
#pragma unroll
            for (int c = 0; c < 4; ++c) {
                float v = acc[t][c][r];
                ps += v * asv[c];
                pd += v * adv[c];
            }
#pragma unroll
            for (int o = 1; o < 16; o <<= 1) {
                ps += __shfl_xor(ps, o);
                pd += __shfl_xor(pd, o);
            }
            if (m16 == 0) {
                int row = wm + t * 16 + quad * 4 + r;
                sdots[row][wn >> 6][0] = ps;
                sdots[row][wn >> 6][1] = pd;
            }
        }
#pragma unroll
    for (int t = 0; t < 2; ++t)
#pragma unroll
        for (int c = 0; c < 4; ++c)
#pragma unroll
            for (int r = 0; r < 4; ++r) {
                int row = n0 + wm + t * 16 + quad * 4 + r;
                if (row < N_NODES)
                    hout[(size_t)row * H_DIM + wn + c * 16 + m16] = (_Float16)acc[t][c][r];
            }
    __syncthreads();
    if (tid < 64) {
        int row = n0 + tid;
        if (row < N_NODES) {
            hs[row] = sdots[tid][0][0] + sdots[tid][1][0];
            hd[row] = sdots[tid][0][1] + sdots[tid][1][1];
        }
    }
}

// One wave per dst node, single-pass softmax; LDS stage for {so,w} broadcast.
// POOL=true fuses only the global max-pool (no device fences — R5 lesson).
template<int DOT, bool POOL>
__global__ void gat_node(const int* __restrict__ row_ptr, const int2* __restrict__ perm,
                         const float* __restrict__ hs, const float* __restrict__ hd,
                         const _Float16* __restrict__ h, const float* __restrict__ bias,
                         _Float16* __restrict__ out,
                         const int* __restrict__ batch, float* __restrict__ pooled) {
    __shared__ float smax[H_DIM];
    __shared__ int sg[4];
    __shared__ __attribute__((aligned(16))) ull stage[4][64];
    int tid = threadIdx.x;
    if (POOL) {
        if (tid < H_DIM) smax[tid] = 0.f;
        __syncthreads();
    }
    int n = blockIdx.x * 4 + (tid >> 6);
    int lane = tid & 63;
    int q = lane >> 4, m = lane & 15;
    int r0 = row_ptr[n], r1 = row_ptr[n + 1];
    float hdn = hd[n];
    const char* hb = (const char*)h;
    unsigned mo = (unsigned)(m * 16);   // lane's byte offset within a row
    ull* st = stage[tid >> 6];

    float acc[8];
#pragma unroll
    for (int k = 0; k < 8; ++k) acc[k] = 0.f;
    float denl = 0.f;

    for (int c = r0; c < r1; c += 64) {
        int i = c + lane;
        float w = 0.f;
        int so = 0;                      // byte offset of src row (fits 32-bit)
        if (i < r1) {
            int2 p = perm[i];
            so = p.x * (H_DIM * 2);
            h2v dv = __builtin_bit_cast(h2v, p.y);
            float dotv = (DOT == 1) ? (float)dv.x : (float)dv.y;
            float t = hs[p.x] + hdn + dotv;
            t = (t > 0.f) ? t : NEG_SLOPE * t;
            w = __expf(t);
        }
        denl += w;
        st[lane] = (ull)(unsigned)so | ((ull)__float_as_uint(w) << 32);
        int lim = r1 - c; if (lim > 64) lim = 64;
        int njj = (lim + 7) >> 3;
        int jj = 0;
        for (; jj + 2 <= njj; jj += 2) {
            int b8 = jj << 3;
            ull p1 = st[b8 + q];
            ull p2 = st[b8 + q + 4];
            ull p3 = st[b8 + q + 8];
            ull p4 = st[b8 + q + 12];
            float w1 = __uint_as_float((unsigned)(p1 >> 32));
            float w2 = __uint_as_float((unsigned)(p2 >> 32));
            float w3 = __uint_as_float((unsigned)(p3 >> 32));
            float w4 = __uint_as_float((unsigned)(p4 >> 32));
            half8 v1 = *(const half8*)(hb + ((unsigned)p1 + mo));
            half8 v2 = *(const half8*)(hb + ((unsigned)p2 + mo));
            half8 v3 = *(const half8*)(hb + ((unsigned)p3 + mo));
            half8 v4 = *(const half8*)(hb + ((unsigned)p4 + mo));
#pragma unroll
            for (int k = 0; k < 8; ++k) acc[k] += w1 * (float)v1[k];
#pragma unroll
            for (int k = 0; k < 8; ++k) acc[k] += w2 * (float)v2[k];
#pragma unroll
            for (int k = 0; k < 8; ++k) acc[k] += w3 * (float)v3[k];
#pragma unroll
            for (int k = 0; k < 8; ++k) acc[k] += w4 * (float)v4[k];
        }
        if (jj < njj) {
            int b8 = jj << 3;
            ull p1 = st[b8 + q];
            ull p2 = st[b8 + q + 4];
            float w1 = __uint_as_float((unsigned)(p1 >> 32));
            float w2 = __uint_as_float((unsigned)(p2 >> 32));
            half8 v1 = *(const half8*)(hb + ((unsigned)p1 + mo));
            half8 v2 = *(const half8*)(hb + ((unsigned)p2 + mo));
#pragma unroll
            for (int k = 0; k < 8; ++k) acc[k] += w1 * (float)v1[k];
#pragma unroll
            for (int k = 0; k < 8; ++k) acc[k] += w2 * (float)v2[k];
        }
    }
#pragma unroll
    for (int k = 0; k < 8; ++k) {
        acc[k] += __shfl_xor(acc[k], 16);
        acc[k] += __shfl_xor(acc[k], 32);
    }
    float den = denl;
#pragma unroll
    for (int o = 32; o > 0; o >>= 1) den += __shfl_xor(den, o);
    float inv = 1.f / fmaxf(den, 1e-16f);

    float rv[8];
    if (q == 0) {
        float4 b0 = ((const float4*)bias)[2 * m];
        float4 b1 = ((const float4*)bias)[2 * m + 1];
        rv[0] = fmaxf(acc[0] * inv + b0.x, 0.f);
        rv[1] = fmaxf(acc[1] * inv + b0.y, 0.f);
        rv[2] = fmaxf(acc[2] * inv + b0.z, 0.f);
        rv[3] = fmaxf(acc[3] * inv + b0.w, 0.f);
        rv[4] = fmaxf(acc[4] * inv + b1.x, 0.f);
        rv[5] = fmaxf(acc[5] * inv + b1.y, 0.f);
        rv[6] = fmaxf(acc[6] * inv + b1.z, 0.f);
        rv[7] = fmaxf(acc[7] * inv + b1.w, 0.f);
    }

    if (!POOL) {
        if (q == 0) {
            half8 ov;
#pragma unroll
            for (int k = 0; k < 8; ++k) ov[k] = (_Float16)rv[k];
            *(half8*)&out[(size_t)n * H_DIM + m * 8] = ov;
        }
    } else {
        int g = batch[n];
        if (lane == 0) sg[tid >> 6] = g;
        if (q == 0) {
#pragma unroll
            for (int k = 0; k < 8; ++k)
                atomicMax((int*)&smax[m * 8 + k], __float_as_int(rv[k]));  // rv >= 0
        }
        __syncthreads();
        if (sg[0] == sg[3]) {
            if (tid < H_DIM)
                atomicMaxFloat(&pooled[sg[0] * H_DIM + tid], smax[tid]);
        } else {
            if (q == 0) {
#pragma unroll
                for (int k = 0; k < 8; ++k)
                    atomicMaxFloat(&pooled[g * H_DIM + m * 8 + k], rv[k]);
            }
        }
    }
}

__global__ void final_logits(const float* __restrict__ pooled, const float* __restrict__ Wl,
                             const float* __restrict__ bl, float* __restrict__ outp) {
    int g = threadIdx.x;  // 64
    if (g >= G_GRAPHS) return;
    float lg[C_CLS];
#pragma unroll
    for (int c = 0; c < C_CLS; ++c) lg[c] = bl[c];
    for (int k = 0; k < H_DIM; ++k) {
        float v = pooled[g * H_DIM + k];
#pragma unroll
        for (int c = 0; c < C_CLS; ++c) lg[c] += v * Wl[k * C_CLS + c];
    }
    float mx = lg[0];
#pragma unroll
    for (int c = 1; c < C_CLS; ++c) mx = fmaxf(mx, lg[c]);
    float se = 0.f;
#pragma unroll
    for (int c = 0; c < C_CLS; ++c) se += expf(lg[c] - mx);
    float lse = logf(se);
#pragma unroll
    for (int c = 0; c < C_CLS; ++c) outp[g * C_CLS + c] = lg[c] - mx - lse;
}

extern "C" void kernel_launch(void* const* d_in, const int* in_sizes, int n_in,
                              void* d_out, int out_size, void* d_ws, size_t ws_size,
                              hipStream_t stream) {
    const float* x     = (const float*)d_in[0];
    const int*   eidx  = (const int*)d_in[1];
    const float* ea    = (const float*)d_in[2];
    const int*   batch = (const int*)d_in[3];
    const float* W1  = (const float*)d_in[4];
    const float* We1 = (const float*)d_in[5];
    const float* as1 = (const float*)d_in[6];
    const float* ad1 = (const float*)d_in[7];
    const float* ae1 = (const float*)d_in[8];
    const float* b1  = (const float*)d_in[9];
    const float* W2  = (const float*)d_in[10];
    const float* We2 = (const float*)d_in[11];
    const float* as2 = (const float*)d_in[12];
    const float* ad2 = (const float*)d_in[13];
    const float* ae2 = (const float*)d_in[14];
    const float* b2  = (const float*)d_in[15];
    const float* Wl  = (const float*)d_in[16];
    const float* bl  = (const float*)d_in[17];
    float* outp = (float*)d_out;

    const int* src = eidx;
    const int* dst = eidx + N_EDGES;

    char* wsb = (char*)d_ws;
    size_t off = 0;
    auto alloc = [&](size_t bytes) { char* p = wsb + off; off += (bytes + 255) & ~(size_t)255; return p; };
    _Float16* h    = (_Float16*)alloc((size_t)N_NODES * H_DIM * 2);
    _Float16* A2   = (_Float16*)alloc((size_t)N_NODES * H_DIM * 2);
    int2*  perm    = (int2*)alloc((size_t)N_EDGES * 8);
    unsigned short* rank = (unsigned short*)alloc((size_t)N_EDGES * 2);
    unsigned int* dotp = (unsigned int*)alloc((size_t)N_EDGES * 4);
    float* hs      = (float*)alloc(N_NODES * 4);
    float* hd      = (float*)alloc(N_NODES * 4);
    int*   row_ptr = (int*)alloc((N_NODES + 1) * 4);
    int4*  cnt4    = (int4*)alloc((size_t)N_NODES * 16);
    int*   excl    = (int*)alloc(N_NODES * 4);
    int*   bsum    = (int*)alloc(SCAN_BLOCKS * 4);
    float* pooled  = (float*)alloc(G_GRAPHS * H_DIM * 4);
    float* ve1     = (float*)alloc(16 * 4);
    float* ve2     = (float*)alloc(16 * 4);
    _Float16* w1t  = (_Float16*)alloc(H_DIM * 96 * 2);
    _Float16* w2t  = (_Float16*)alloc(H_DIM * H_DIM * 2);

    const int NB4 = (N_NODES + 3) / 4;

    // prep (incl. W1t/W2t transpose), then conv1-GEMM overlapped with hist+dots
    prep<<<SCAN_BLOCKS + 3, 256, 0, stream>>>(cnt4, pooled, We1, ae1, We2, ae2,
                                              ve1, ve2, W1, W2, w1t, w2t);
    gemm1_hist<<<GB_BLOCKS + HB_BLOCKS, 256, 0, stream>>>(x, w1t, as1, ad1, h, hs, hd,
                                                          dst, (int*)cnt4, rank, ea,
                                                          ve1, ve2, dotp);
    scan1<<<SCAN_BLOCKS, 256, 0, stream>>>(cnt4, excl, bsum);
    scan_scatter<<<EB_BLOCKS, 256, 0, stream>>>(excl, bsum, row_ptr, src, dst,
                                                rank, cnt4, dotp, perm);

    // ---- conv1 aggregation ----
    gat_node<1, false><<<NB4, 256, 0, stream>>>(row_ptr, perm, hs, hd, h, b1, A2,
                                                batch, pooled);

    // ---- conv2 ----
    gemm2<<<GB_BLOCKS, 256, 0, stream>>>(A2, w2t, as2, ad2, h, hs, hd);
    gat_node<2, true><<<NB4, 256, 0, stream>>>(row_ptr, perm, hs, hd, h, b2, nullptr,
                                               batch, pooled);

    // ---- classifier ----
    final_logits<<<1, 64, 0, stream>>>(pooled, Wl, bl, outp);
}